// Round 7
// baseline (269.589 us; speedup 1.0000x reference)
//
#include <hip/hip_runtime.h>
#include <math.h>

// TopoBrainPhysical fused forward, round 7.
// Two-kernel split (R6 win) + operand-path fixes:
// K1 (encoder+corners+mixing): 1 thread/elem; ALL weights staged in 3.2KB LDS,
//     read as immediate-offset ds_read_b128 broadcasts (R2/R3 post-mortem: big
//     uniform weight tables become per-lane VMEM + VALU addr calc, ~3x issue
//     bloat). Writes z,mc,mw as SoA float4 chunks to d_ws (coalesced).
// K2 (node MLP + readout): 4 lanes/elem, 2 cells/lane, and TWO elements per
//     thread so every weight ds_read feeds FMAs for both elements (k2 was
//     LDS-pipe-bound: 1 LDS unit/CU shared by 4 SIMDs). waves_per_eu(4,4)
//     pins the 128-VGPR budget (live ~115; R4 spill lesson).
// All register arrays statically indexed. Fallback fused kernel if ws small.

#define PI_F 3.14159265358979323846f

__device__ __forceinline__ float fast_tanh(float v) {
    float e = __expf(2.0f * v);
    return 1.0f - 2.0f * __builtin_amdgcn_rcpf(e + 1.0f);
}

// butterfly sum over the 4 lanes of a quad; all lanes get the total.
__device__ __forceinline__ float quad_sum(float x) {
    x += __int_as_float(__builtin_amdgcn_update_dpp(
             0, __float_as_int(x), 0xB1, 0xF, 0xF, true)); // {1,0,3,2}
    x += __int_as_float(__builtin_amdgcn_update_dpp(
             0, __float_as_int(x), 0x4E, 0xF, 0xF, true)); // {2,3,0,1}
    return x;
}

// ===================== kernel 1 =====================
// LDS float layout:
// EW1[4][24]@0  EB1[24]@96  EW2[24][24]@120  EB2[24]@696  EW3T[3][24]@720
// EB3[3]@792  (total 796 -> 800)
#define K1_LDS 800

extern "C" __global__ void __launch_bounds__(256, 2)
topo_k1(const float* __restrict__ x,
        const float* __restrict__ ew1, const float* __restrict__ eb1,
        const float* __restrict__ ew2, const float* __restrict__ eb2,
        const float* __restrict__ ew3, const float* __restrict__ eb3,
        const float* __restrict__ alog, const float* __restrict__ rlog,
        float* __restrict__ ws, int B)
{
    __shared__ float wf[K1_LDS];
    const float4* wq = reinterpret_cast<const float4*>(wf);
    {
        const int tt = threadIdx.x;
        for (int i = tt; i < 96;  i += 256) wf[i]       = ew1[i];
        for (int i = tt; i < 24;  i += 256) wf[96 + i]  = eb1[i];
        for (int i = tt; i < 576; i += 256) wf[120 + i] = ew2[i];
        for (int i = tt; i < 24;  i += 256) wf[696 + i] = eb2[i];
        for (int i = tt; i < 72;  i += 256) wf[720 + (i % 3) * 24 + (i / 3)] = ew3[i];
        for (int i = tt; i < 3;   i += 256) wf[792 + i] = eb3[i];
    }
    __syncthreads();

    const int b = blockIdx.x * blockDim.x + threadIdx.x;
    if (b >= B) return;

    // ---- normalized adjacency (wave-uniform; 6 scalar global reads) ----
    float ang[4][4];
    {
        float m = fmaxf(fmaxf(alog[0], alog[1]), fmaxf(alog[2], alog[3]));
        float e0 = __expf(alog[0] - m), e1 = __expf(alog[1] - m);
        float e2 = __expf(alog[2] - m), e3 = __expf(alog[3] - m);
        float s = e0 + e1 + e2 + e3;
        float sm[4] = { e0 / s, e1 / s, e2 / s, e3 / s };
        #pragma unroll
        for (int i = 0; i < 4; ++i) {
            const int jn = (i + 3) & 3, jp = (i + 1) & 3;
            float inv = 1.0f / fmaxf(sm[jn] + sm[jp], 1e-6f);
            #pragma unroll
            for (int j = 0; j < 4; ++j) {
                float adj = (j == jn || j == jp) ? 1.0f : 0.0f;
                ang[i][j] = sm[j] * adj * inv;
            }
        }
    }
    float rad[2][2];
    {
        float m = fmaxf(rlog[0], rlog[1]);
        float f0 = __expf(rlog[0] - m), f1 = __expf(rlog[1] - m);
        float fs = f0 + f1;
        float sm0 = f0 / fs, sm1 = f1 / fs;
        rad[0][0] = 0.0f; rad[0][1] = sm1 / fmaxf(sm1, 1e-6f);
        rad[1][1] = 0.0f; rad[1][0] = sm0 / fmaxf(sm0, 1e-6f);
    }

    const float4 xv = *reinterpret_cast<const float4*>(x + (size_t)b * 60 + 56);

    // ---- encoder layer 1 ----
    float zt[24];
    #pragma unroll
    for (int c = 0; c < 6; ++c) {
        float4 b4 = wq[24 + c];
        float4 w0 = wq[c],      w1 = wq[6 + c];
        float4 w2 = wq[12 + c], w3 = wq[18 + c];
        zt[c*4+0] = fast_tanh(b4.x + xv.x*w0.x + xv.y*w1.x + xv.z*w2.x + xv.w*w3.x);
        zt[c*4+1] = fast_tanh(b4.y + xv.x*w0.y + xv.y*w1.y + xv.z*w2.y + xv.w*w3.y);
        zt[c*4+2] = fast_tanh(b4.z + xv.x*w0.z + xv.y*w1.z + xv.z*w2.z + xv.w*w3.z);
        zt[c*4+3] = fast_tanh(b4.w + xv.x*w0.w + xv.y*w1.w + xv.z*w2.w + xv.w*w3.w);
    }

    // ---- encoder layer 2 (24x24) ----
    float a2[24];
    #pragma unroll
    for (int c = 0; c < 6; ++c) {
        float4 b4 = wq[174 + c];   // eb2 @696
        a2[c*4+0] = b4.x; a2[c*4+1] = b4.y; a2[c*4+2] = b4.z; a2[c*4+3] = b4.w;
    }
    #pragma unroll
    for (int k = 0; k < 24; ++k) {
        const float zk = zt[k];
        #pragma unroll
        for (int c = 0; c < 6; ++c) {
            float4 wv = wq[30 + k * 6 + c];   // ew2 row k @120
            a2[c*4+0] += zk * wv.x; a2[c*4+1] += zk * wv.y;
            a2[c*4+2] += zk * wv.z; a2[c*4+3] += zk * wv.w;
        }
    }
    float zt2[24];
    #pragma unroll
    for (int j = 0; j < 24; ++j) zt2[j] = fast_tanh(a2[j]);

    // ---- encoder layer 3 (24x3, transposed) ----
    float z0 = wf[792], z1 = wf[793], z2 = wf[794];
    #pragma unroll
    for (int c = 0; c < 6; ++c) {
        float4 v0 = wq[180 + c], v1 = wq[186 + c], v2 = wq[192 + c];
        z0 += zt2[c*4+0]*v0.x + zt2[c*4+1]*v0.y + zt2[c*4+2]*v0.z + zt2[c*4+3]*v0.w;
        z1 += zt2[c*4+0]*v1.x + zt2[c*4+1]*v1.y + zt2[c*4+2]*v1.z + zt2[c*4+3]*v1.w;
        z2 += zt2[c*4+0]*v2.x + zt2[c*4+1]*v2.y + zt2[c*4+2]*v2.z + zt2[c*4+3]*v2.w;
    }

    // ---- bilinear corners ----
    const float r = 1.0f / (1.0f + __expf(-z0));
    const float p = (z1 + PI_F) / (2.0f * PI_F) * 4.0f;
    const float r0f = truncf(r), p0f = truncf(p);
    const float dr = r - r0f, dp = p - p0f;
    const int r0i = (int)r0f, p0i = (int)p0f;

    const float w0c = (1.0f - dr) * (1.0f - dp);
    const float w1c = (1.0f - dr) * dp;
    const float w2c = dr * (1.0f - dp);
    const float w3c = dr * dp;

    const int ri0 = min(r0i, 1);
    const int ri2 = min(r0i + 1, 1);
    const int pi0 = p0i & 3;
    const int pi1 = (p0i + 1) & 3;

    const int c0 = ri0 * 4 + pi0, c1 = ri0 * 4 + pi1;
    const int c2 = ri2 * 4 + pi0, c3 = ri2 * 4 + pi1;

    float cnt[8], wsum[8];
    #pragma unroll
    for (int n = 0; n < 8; ++n) {
        float cm = 0.0f, cw = 0.0f;
        if (c0 == n && w0c > 0.0f) { cm += 1.0f; cw += w0c; }
        if (c1 == n && w1c > 0.0f) { cm += 1.0f; cw += w1c; }
        if (c2 == n && w2c > 0.0f) { cm += 1.0f; cw += w2c; }
        if (c3 == n && w3c > 0.0f) { cm += 1.0f; cw += w3c; }
        cnt[n] = cm; wsum[n] = cw;
    }
    float mc[8], mw[8];
    #pragma unroll
    for (int n = 0; n < 8; ++n) {
        float ac = cnt[n], aw = wsum[n];
        #pragma unroll
        for (int j = 0; j < 4; ++j) {
            const float g = ang[n >> 1][j];
            ac += g * cnt[2 * j + (n & 1)];
            aw += g * wsum[2 * j + (n & 1)];
        }
        #pragma unroll
        for (int j = 0; j < 2; ++j) {
            const float g = rad[n >> 2][j];
            ac += g * cnt[4 * j + (n & 3)];
            aw += g * wsum[4 * j + (n & 3)];
        }
        mc[n] = ac; mw[n] = aw;
    }

    // ---- SoA float4 store: chunk i at W[i*B + b] ----
    float4* W = reinterpret_cast<float4*>(ws);
    float4 v0; v0.x = z0;    v0.y = z1;    v0.z = z2;    v0.w = 0.0f;
    float4 v1; v1.x = mc[0]; v1.y = mc[1]; v1.z = mc[2]; v1.w = mc[3];
    float4 v2; v2.x = mc[4]; v2.y = mc[5]; v2.z = mc[6]; v2.w = mc[7];
    float4 v3; v3.x = mw[0]; v3.y = mw[1]; v3.z = mw[2]; v3.w = mw[3];
    float4 v4; v4.x = mw[4]; v4.y = mw[5]; v4.z = mw[6]; v4.w = mw[7];
    W[0 * (size_t)B + b] = v0;
    W[1 * (size_t)B + b] = v1;
    W[2 * (size_t)B + b] = v2;
    W[3 * (size_t)B + b] = v3;
    W[4 * (size_t)B + b] = v4;
}

// ===================== kernel 2 =====================
// LDS float layout (R6-identical):
// NW1[4][24]@0  NB1[24]@96  NW2[24][12]@120  NB2[12]@408
// RW1 8 cells x (12x24), cell stride padded 288->296 @420
// RB1[24]@2788  RW2[24][4]@2812  RB2[4]@2908  -> 2912 floats
#define K2_LDS 2912

extern "C" __global__
__attribute__((amdgpu_flat_work_group_size(256, 256)))
__attribute__((amdgpu_waves_per_eu(4, 4)))
void topo_k2(const float* __restrict__ ws,
        const float* __restrict__ nw1, const float* __restrict__ nb1,
        const float* __restrict__ nw2, const float* __restrict__ nb2,
        const float* __restrict__ rw1, const float* __restrict__ rb1,
        const float* __restrict__ rw2, const float* __restrict__ rb2,
        float* __restrict__ out, int B)
{
    __shared__ float wf[K2_LDS];
    const float4* wq = reinterpret_cast<const float4*>(wf);
    {
        const int tt = threadIdx.x;
        for (int i = tt; i < 96;   i += 256) wf[i]        = nw1[i];
        for (int i = tt; i < 24;   i += 256) wf[96 + i]   = nb1[i];
        for (int i = tt; i < 288;  i += 256) wf[120 + i]  = nw2[i];
        for (int i = tt; i < 12;   i += 256) wf[408 + i]  = nb2[i];
        for (int i = tt; i < 2304; i += 256) {
            const int cell = i / 288, rem = i - cell * 288;
            wf[420 + cell * 296 + rem] = rw1[i];
        }
        for (int i = tt; i < 24;   i += 256) wf[2788 + i] = rb1[i];
        for (int i = tt; i < 96;   i += 256) wf[2812 + i] = rw2[i];
        for (int i = tt; i < 4;    i += 256) wf[2908 + i] = rb2[i];
    }
    __syncthreads();

    const int tid  = blockIdx.x * blockDim.x + threadIdx.x;
    const int lane = tid & 3;           // owns cells 2*lane, 2*lane+1
    const int pr   = tid >> 2;          // element pair
    const int nP   = (B + 1) >> 1;
    if (pr >= nP) return;
    const int e0 = 2 * pr;
    const int e1e = 2 * pr + 1;
    const int e1 = (e1e < B) ? e1e : (B - 1);   // clamp for odd B

    // ---- per-element state from SoA ws ----
    const float4* Wv = reinterpret_cast<const float4*>(ws);
    const float4 zA = Wv[e0];
    const float4 zB = Wv[e1];
    const int chMC = 1 + (lane >> 1), chMW = 3 + (lane >> 1);
    const int sub  = (lane & 1) * 2;
    const float2 mcA2 = *reinterpret_cast<const float2*>(ws + (size_t)chMC * B * 4 + (size_t)e0 * 4 + sub);
    const float2 mwA2 = *reinterpret_cast<const float2*>(ws + (size_t)chMW * B * 4 + (size_t)e0 * 4 + sub);
    const float2 mcB2 = *reinterpret_cast<const float2*>(ws + (size_t)chMC * B * 4 + (size_t)e1 * 4 + sub);
    const float2 mwB2 = *reinterpret_cast<const float2*>(ws + (size_t)chMW * B * 4 + (size_t)e1 * 4 + sub);

    float t0[24], t1[24];
    #pragma unroll
    for (int j = 0; j < 24; ++j) { t0[j] = 0.0f; t1[j] = 0.0f; }

    #pragma unroll
    for (int cc = 0; cc < 2; ++cc) {
        const float mcA = cc ? mcA2.y : mcA2.x;
        const float mwA = cc ? mwA2.y : mwA2.x;
        const float mcB = cc ? mcB2.y : mcB2.x;
        const float mwB = cc ? mwB2.y : mwB2.x;
        const float fA0 = mcA * zA.x, fA1 = mcA * zA.y, fA2 = mcA * zA.z;
        const float fB0 = mcB * zB.x, fB1 = mcB * zB.y, fB2 = mcB * zB.z;

        float hoA[12], hoB[12];
        {
            float4 bA = wq[102], bB = wq[103], bC = wq[104];
            hoA[0] = bA.x; hoA[1]  = bA.y; hoA[2]  = bA.z; hoA[3]  = bA.w;
            hoA[4] = bB.x; hoA[5]  = bB.y; hoA[6]  = bB.z; hoA[7]  = bB.w;
            hoA[8] = bC.x; hoA[9]  = bC.y; hoA[10] = bC.z; hoA[11] = bC.w;
            #pragma unroll
            for (int d = 0; d < 12; ++d) hoB[d] = hoA[d];
        }
        #pragma unroll
        for (int c = 0; c < 6; ++c) {
            float4 b1 = wq[24 + c];
            float4 u0 = wq[c],      u1 = wq[6 + c];
            float4 u2 = wq[12 + c], u3 = wq[18 + c];
            float hA[4], hB[4];
            hA[0] = fast_tanh(b1.x + fA0*u0.x + fA1*u1.x + fA2*u2.x + mwA*u3.x);
            hA[1] = fast_tanh(b1.y + fA0*u0.y + fA1*u1.y + fA2*u2.y + mwA*u3.y);
            hA[2] = fast_tanh(b1.z + fA0*u0.z + fA1*u1.z + fA2*u2.z + mwA*u3.z);
            hA[3] = fast_tanh(b1.w + fA0*u0.w + fA1*u1.w + fA2*u2.w + mwA*u3.w);
            hB[0] = fast_tanh(b1.x + fB0*u0.x + fB1*u1.x + fB2*u2.x + mwB*u3.x);
            hB[1] = fast_tanh(b1.y + fB0*u0.y + fB1*u1.y + fB2*u2.y + mwB*u3.y);
            hB[2] = fast_tanh(b1.z + fB0*u0.z + fB1*u1.z + fB2*u2.z + mwB*u3.z);
            hB[3] = fast_tanh(b1.w + fB0*u0.w + fB1*u1.w + fB2*u2.w + mwB*u3.w);
            #pragma unroll
            for (int jj = 0; jj < 4; ++jj) {
                const int j = c * 4 + jj;
                const float ha = hA[jj], hb = hB[jj];
                float4 n0 = wq[30 + j * 3], n1 = wq[31 + j * 3], n2 = wq[32 + j * 3];
                hoA[0] += ha*n0.x; hoA[1]  += ha*n0.y; hoA[2]  += ha*n0.z; hoA[3]  += ha*n0.w;
                hoA[4] += ha*n1.x; hoA[5]  += ha*n1.y; hoA[6]  += ha*n1.z; hoA[7]  += ha*n1.w;
                hoA[8] += ha*n2.x; hoA[9]  += ha*n2.y; hoA[10] += ha*n2.z; hoA[11] += ha*n2.w;
                hoB[0] += hb*n0.x; hoB[1]  += hb*n0.y; hoB[2]  += hb*n0.z; hoB[3]  += hb*n0.w;
                hoB[4] += hb*n1.x; hoB[5]  += hb*n1.y; hoB[6]  += hb*n1.z; hoB[7]  += hb*n1.w;
                hoB[8] += hb*n2.x; hoB[9]  += hb*n2.y; hoB[10] += hb*n2.z; hoB[11] += hb*n2.w;
            }
        }
        // t += ho . rw1[cell]; shared rv reads feed both elements
        const int qb0 = 105 + (2 * lane + cc) * 74;   // 420/4 + cell*296/4
        #pragma unroll
        for (int d = 0; d < 12; ++d) {
            const float ha = hoA[d], hb = hoB[d];
            #pragma unroll
            for (int c = 0; c < 6; ++c) {
                float4 rv = wq[qb0 + d * 6 + c];
                t0[c*4+0] += ha * rv.x; t0[c*4+1] += ha * rv.y;
                t0[c*4+2] += ha * rv.z; t0[c*4+3] += ha * rv.w;
                t1[c*4+0] += hb * rv.x; t1[c*4+1] += hb * rv.y;
                t1[c*4+2] += hb * rv.z; t1[c*4+3] += hb * rv.w;
            }
        }
        __builtin_amdgcn_sched_barrier(0);
    }

    // ---- reduce across 4 lanes; add rb1 ----
    #pragma unroll
    for (int j = 0; j < 24; ++j) {
        const float rbj = wf[2788 + j];
        t0[j] = quad_sum(t0[j]) + rbj;
        t1[j] = quad_sum(t1[j]) + rbj;
    }

    // ---- readout layer 2 (shared rv reads; lane 0 stores both) ----
    float4 ob = wq[727];
    float o00 = ob.x, o01 = ob.y, o02 = ob.z, o03 = ob.w;
    float o10 = ob.x, o11 = ob.y, o12 = ob.z, o13 = ob.w;
    #pragma unroll
    for (int j = 0; j < 24; ++j) {
        const float ta = fast_tanh(t0[j]);
        const float tb = fast_tanh(t1[j]);
        float4 rv = wq[703 + j];
        o00 += ta * rv.x; o01 += ta * rv.y; o02 += ta * rv.z; o03 += ta * rv.w;
        o10 += tb * rv.x; o11 += tb * rv.y; o12 += tb * rv.z; o13 += tb * rv.w;
    }
    if (lane == 0) {
        float4 ovA; ovA.x = o00; ovA.y = o01; ovA.z = o02; ovA.w = o03;
        *reinterpret_cast<float4*>(out + (size_t)e0 * 4) = ovA;
        if (e1e < B) {
            float4 ovB; ovB.x = o10; ovB.y = o11; ovB.z = o12; ovB.w = o13;
            *reinterpret_cast<float4*>(out + (size_t)e1e * 4) = ovB;
        }
    }
}

// ===================== fallback fused kernel =====================
extern "C" __global__ void __launch_bounds__(256, 2)
topo_fused(const float* __restrict__ x,
           const float* __restrict__ ew1, const float* __restrict__ eb1,
           const float* __restrict__ ew2, const float* __restrict__ eb2,
           const float* __restrict__ ew3, const float* __restrict__ eb3,
           const float* __restrict__ nw1, const float* __restrict__ nb1,
           const float* __restrict__ nw2, const float* __restrict__ nb2,
           const float* __restrict__ alog, const float* __restrict__ rlog,
           const float* __restrict__ rw1, const float* __restrict__ rb1,
           const float* __restrict__ rw2, const float* __restrict__ rb2,
           float* __restrict__ out, int B)
{
    const int b = blockIdx.x * blockDim.x + threadIdx.x;
    if (b >= B) return;

    float ang[4][4];
    {
        float m = fmaxf(fmaxf(alog[0], alog[1]), fmaxf(alog[2], alog[3]));
        float e0 = __expf(alog[0] - m), e1 = __expf(alog[1] - m);
        float e2 = __expf(alog[2] - m), e3 = __expf(alog[3] - m);
        float s = e0 + e1 + e2 + e3;
        float sm[4] = { e0 / s, e1 / s, e2 / s, e3 / s };
        #pragma unroll
        for (int i = 0; i < 4; ++i) {
            const int jn = (i + 3) & 3, jp = (i + 1) & 3;
            float inv = 1.0f / fmaxf(sm[jn] + sm[jp], 1e-6f);
            #pragma unroll
            for (int j = 0; j < 4; ++j) {
                float adj = (j == jn || j == jp) ? 1.0f : 0.0f;
                ang[i][j] = sm[j] * adj * inv;
            }
        }
    }
    float rad[2][2];
    {
        float m = fmaxf(rlog[0], rlog[1]);
        float f0 = __expf(rlog[0] - m), f1 = __expf(rlog[1] - m);
        float fs = f0 + f1;
        float sm0 = f0 / fs, sm1 = f1 / fs;
        rad[0][0] = 0.0f; rad[0][1] = sm1 / fmaxf(sm1, 1e-6f);
        rad[1][1] = 0.0f; rad[1][0] = sm0 / fmaxf(sm0, 1e-6f);
    }

    const float4 xv = *reinterpret_cast<const float4*>(x + (size_t)b * 60 + 56);
    float zt[24];
    #pragma unroll
    for (int j = 0; j < 24; ++j) {
        float a = eb1[j];
        a += xv.x * ew1[j];
        a += xv.y * ew1[24 + j];
        a += xv.z * ew1[48 + j];
        a += xv.w * ew1[72 + j];
        zt[j] = fast_tanh(a);
    }
    float z0 = eb3[0], z1 = eb3[1], z2 = eb3[2];
    #pragma unroll
    for (int j = 0; j < 24; ++j) {
        float a = eb2[j];
        #pragma unroll
        for (int k = 0; k < 24; ++k) a += zt[k] * ew2[k * 24 + j];
        const float z2t = fast_tanh(a);
        z0 += z2t * ew3[j * 3 + 0];
        z1 += z2t * ew3[j * 3 + 1];
        z2 += z2t * ew3[j * 3 + 2];
    }

    const float r = 1.0f / (1.0f + __expf(-z0));
    const float p = (z1 + PI_F) / (2.0f * PI_F) * 4.0f;
    const float r0f = truncf(r), p0f = truncf(p);
    const float dr = r - r0f, dp = p - p0f;
    const int r0i = (int)r0f, p0i = (int)p0f;
    const float w0c = (1.0f - dr) * (1.0f - dp);
    const float w1c = (1.0f - dr) * dp;
    const float w2c = dr * (1.0f - dp);
    const float w3c = dr * dp;
    const int ri0 = min(r0i, 1);
    const int ri2 = min(r0i + 1, 1);
    const int pi0 = p0i & 3;
    const int pi1 = (p0i + 1) & 3;
    const int c0 = ri0 * 4 + pi0, c1 = ri0 * 4 + pi1;
    const int c2 = ri2 * 4 + pi0, c3 = ri2 * 4 + pi1;

    float cnt[8], wsum[8];
    #pragma unroll
    for (int n = 0; n < 8; ++n) {
        float cm = 0.0f, cw = 0.0f;
        if (c0 == n && w0c > 0.0f) { cm += 1.0f; cw += w0c; }
        if (c1 == n && w1c > 0.0f) { cm += 1.0f; cw += w1c; }
        if (c2 == n && w2c > 0.0f) { cm += 1.0f; cw += w2c; }
        if (c3 == n && w3c > 0.0f) { cm += 1.0f; cw += w3c; }
        cnt[n] = cm; wsum[n] = cw;
    }
    float mc[8], mw[8];
    #pragma unroll
    for (int n = 0; n < 8; ++n) {
        float ac = cnt[n], aw = wsum[n];
        #pragma unroll
        for (int j = 0; j < 4; ++j) {
            const float g = ang[n >> 1][j];
            ac += g * cnt[2 * j + (n & 1)];
            aw += g * wsum[2 * j + (n & 1)];
        }
        #pragma unroll
        for (int j = 0; j < 2; ++j) {
            const float g = rad[n >> 2][j];
            ac += g * cnt[4 * j + (n & 3)];
            aw += g * wsum[4 * j + (n & 3)];
        }
        mc[n] = ac; mw[n] = aw;
    }

    float t[24];
    #pragma unroll
    for (int j = 0; j < 24; ++j) t[j] = rb1[j];
    #pragma unroll
    for (int n = 0; n < 8; ++n) {
        const float f0 = mc[n] * z0, f1 = mc[n] * z1, f2 = mc[n] * z2;
        float ho[12];
        #pragma unroll
        for (int d = 0; d < 12; ++d) ho[d] = nb2[d];
        #pragma unroll
        for (int j = 0; j < 24; ++j) {
            const float hj = fast_tanh(nb1[j] + f0 * nw1[j] + f1 * nw1[24 + j]
                                       + f2 * nw1[48 + j] + mw[n] * nw1[72 + j]);
            #pragma unroll
            for (int d = 0; d < 12; ++d) ho[d] += hj * nw2[j * 12 + d];
        }
        #pragma unroll
        for (int d = 0; d < 12; ++d) {
            const int rbase = (n * 12 + d) * 24;
            #pragma unroll
            for (int j2 = 0; j2 < 24; ++j2) t[j2] += ho[d] * rw1[rbase + j2];
        }
    }

    float o0 = rb2[0], o1 = rb2[1], o2 = rb2[2], o3 = rb2[3];
    #pragma unroll
    for (int j = 0; j < 24; ++j) {
        const float tt = fast_tanh(t[j]);
        o0 += tt * rw2[j * 4 + 0];
        o1 += tt * rw2[j * 4 + 1];
        o2 += tt * rw2[j * 4 + 2];
        o3 += tt * rw2[j * 4 + 3];
    }
    float4 ov; ov.x = o0; ov.y = o1; ov.z = o2; ov.w = o3;
    *reinterpret_cast<float4*>(out + (size_t)b * 4) = ov;
}

extern "C" void kernel_launch(void* const* d_in, const int* in_sizes, int n_in,
                              void* d_out, int out_size, void* d_ws, size_t ws_size,
                              hipStream_t stream) {
    const float* x    = (const float*)d_in[0];
    const float* ew1  = (const float*)d_in[1];
    const float* eb1  = (const float*)d_in[2];
    const float* ew2  = (const float*)d_in[3];
    const float* eb2  = (const float*)d_in[4];
    const float* ew3  = (const float*)d_in[5];
    const float* eb3  = (const float*)d_in[6];
    const float* nw1  = (const float*)d_in[7];
    const float* nb1  = (const float*)d_in[8];
    const float* nw2  = (const float*)d_in[9];
    const float* nb2  = (const float*)d_in[10];
    const float* alog = (const float*)d_in[11];
    const float* rlog = (const float*)d_in[12];
    const float* rw1  = (const float*)d_in[13];
    const float* rb1  = (const float*)d_in[14];
    const float* rw2  = (const float*)d_in[15];
    const float* rb2  = (const float*)d_in[16];
    float* out = (float*)d_out;

    const int B = in_sizes[0] / 60;   // x is (B, 15, 4)
    const size_t ws_needed = (size_t)B * 20 * sizeof(float);

    if (ws_size >= ws_needed) {
        float* ws = (float*)d_ws;
        const int g1 = (B + 255) / 256;
        topo_k1<<<g1, 256, 0, stream>>>(x, ew1, eb1, ew2, eb2, ew3, eb3,
                                        alog, rlog, ws, B);
        const long long tot2 = ((long long)B + 1) / 2 * 4;
        const int g2 = (int)((tot2 + 255) / 256);
        topo_k2<<<g2, 256, 0, stream>>>(ws, nw1, nb1, nw2, nb2,
                                        rw1, rb1, rw2, rb2, out, B);
    } else {
        const int g = (B + 255) / 256;
        topo_fused<<<g, 256, 0, stream>>>(
            x, ew1, eb1, ew2, eb2, ew3, eb3, nw1, nb1, nw2, nb2,
            alog, rlog, rw1, rb1, rw2, rb2, out, B);
    }
}

// Round 8
// 51.613 us; speedup vs baseline: 5.2233x; 5.2233x over previous
//
#include <hip/hip_runtime.h>
#include <math.h>

// TopoBrainPhysical fused forward, round 8.
// ROLLBACK+KEEP: k2 reverts verbatim to R6 (single elem per quad, 2 cells/
// lane, live ~60 regs -- proven no-spill at the compiler's ~64-VGPR pin).
// k1 keeps R7's LDS-staged encoder (unmeasured; live ~60 fits the pin).
// Cross-round lesson [HIP-compiler]: this hipcc pins these kernels at ~64
// VGPR regardless of waves_per_eu/launch_bounds hints; any live set > ~64
// spills to scratch (R2 10MB, R4 1.4GB, R7 0.9GB). Design for <=64 live.

#define PI_F 3.14159265358979323846f

__device__ __forceinline__ float fast_tanh(float v) {
    float e = __expf(2.0f * v);
    return 1.0f - 2.0f * __builtin_amdgcn_rcpf(e + 1.0f);
}

// butterfly sum over the 4 lanes of a quad; all lanes get the total.
__device__ __forceinline__ float quad_sum(float x) {
    x += __int_as_float(__builtin_amdgcn_update_dpp(
             0, __float_as_int(x), 0xB1, 0xF, 0xF, true)); // {1,0,3,2}
    x += __int_as_float(__builtin_amdgcn_update_dpp(
             0, __float_as_int(x), 0x4E, 0xF, 0xF, true)); // {2,3,0,1}
    return x;
}

// ===================== kernel 1 =====================
// LDS float layout:
// EW1[4][24]@0  EB1[24]@96  EW2[24][24]@120  EB2[24]@696  EW3T[3][24]@720
// EB3[3]@792  (total 796 -> 800)
#define K1_LDS 800

extern "C" __global__ void __launch_bounds__(256, 2)
topo_k1(const float* __restrict__ x,
        const float* __restrict__ ew1, const float* __restrict__ eb1,
        const float* __restrict__ ew2, const float* __restrict__ eb2,
        const float* __restrict__ ew3, const float* __restrict__ eb3,
        const float* __restrict__ alog, const float* __restrict__ rlog,
        float* __restrict__ ws, int B)
{
    __shared__ float wf[K1_LDS];
    const float4* wq = reinterpret_cast<const float4*>(wf);
    {
        const int tt = threadIdx.x;
        for (int i = tt; i < 96;  i += 256) wf[i]       = ew1[i];
        for (int i = tt; i < 24;  i += 256) wf[96 + i]  = eb1[i];
        for (int i = tt; i < 576; i += 256) wf[120 + i] = ew2[i];
        for (int i = tt; i < 24;  i += 256) wf[696 + i] = eb2[i];
        for (int i = tt; i < 72;  i += 256) wf[720 + (i % 3) * 24 + (i / 3)] = ew3[i];
        for (int i = tt; i < 3;   i += 256) wf[792 + i] = eb3[i];
    }
    __syncthreads();

    const int b = blockIdx.x * blockDim.x + threadIdx.x;
    if (b >= B) return;

    // ---- normalized adjacency (wave-uniform; 6 scalar global reads) ----
    float ang[4][4];
    {
        float m = fmaxf(fmaxf(alog[0], alog[1]), fmaxf(alog[2], alog[3]));
        float e0 = __expf(alog[0] - m), e1 = __expf(alog[1] - m);
        float e2 = __expf(alog[2] - m), e3 = __expf(alog[3] - m);
        float s = e0 + e1 + e2 + e3;
        float sm[4] = { e0 / s, e1 / s, e2 / s, e3 / s };
        #pragma unroll
        for (int i = 0; i < 4; ++i) {
            const int jn = (i + 3) & 3, jp = (i + 1) & 3;
            float inv = 1.0f / fmaxf(sm[jn] + sm[jp], 1e-6f);
            #pragma unroll
            for (int j = 0; j < 4; ++j) {
                float adj = (j == jn || j == jp) ? 1.0f : 0.0f;
                ang[i][j] = sm[j] * adj * inv;
            }
        }
    }
    float rad[2][2];
    {
        float m = fmaxf(rlog[0], rlog[1]);
        float f0 = __expf(rlog[0] - m), f1 = __expf(rlog[1] - m);
        float fs = f0 + f1;
        float sm0 = f0 / fs, sm1 = f1 / fs;
        rad[0][0] = 0.0f; rad[0][1] = sm1 / fmaxf(sm1, 1e-6f);
        rad[1][1] = 0.0f; rad[1][0] = sm0 / fmaxf(sm0, 1e-6f);
    }

    const float4 xv = *reinterpret_cast<const float4*>(x + (size_t)b * 60 + 56);

    // ---- encoder layer 1 ----
    float zt[24];
    #pragma unroll
    for (int c = 0; c < 6; ++c) {
        float4 b4 = wq[24 + c];
        float4 w0 = wq[c],      w1 = wq[6 + c];
        float4 w2 = wq[12 + c], w3 = wq[18 + c];
        zt[c*4+0] = fast_tanh(b4.x + xv.x*w0.x + xv.y*w1.x + xv.z*w2.x + xv.w*w3.x);
        zt[c*4+1] = fast_tanh(b4.y + xv.x*w0.y + xv.y*w1.y + xv.z*w2.y + xv.w*w3.y);
        zt[c*4+2] = fast_tanh(b4.z + xv.x*w0.z + xv.y*w1.z + xv.z*w2.z + xv.w*w3.z);
        zt[c*4+3] = fast_tanh(b4.w + xv.x*w0.w + xv.y*w1.w + xv.z*w2.w + xv.w*w3.w);
    }

    // ---- encoder layer 2 (24x24) ----
    float a2[24];
    #pragma unroll
    for (int c = 0; c < 6; ++c) {
        float4 b4 = wq[174 + c];   // eb2 @696
        a2[c*4+0] = b4.x; a2[c*4+1] = b4.y; a2[c*4+2] = b4.z; a2[c*4+3] = b4.w;
    }
    #pragma unroll
    for (int k = 0; k < 24; ++k) {
        const float zk = zt[k];
        #pragma unroll
        for (int c = 0; c < 6; ++c) {
            float4 wv = wq[30 + k * 6 + c];   // ew2 row k @120
            a2[c*4+0] += zk * wv.x; a2[c*4+1] += zk * wv.y;
            a2[c*4+2] += zk * wv.z; a2[c*4+3] += zk * wv.w;
        }
    }
    float zt2[24];
    #pragma unroll
    for (int j = 0; j < 24; ++j) zt2[j] = fast_tanh(a2[j]);

    // ---- encoder layer 3 (24x3, transposed) ----
    float z0 = wf[792], z1 = wf[793], z2 = wf[794];
    #pragma unroll
    for (int c = 0; c < 6; ++c) {
        float4 v0 = wq[180 + c], v1 = wq[186 + c], v2 = wq[192 + c];
        z0 += zt2[c*4+0]*v0.x + zt2[c*4+1]*v0.y + zt2[c*4+2]*v0.z + zt2[c*4+3]*v0.w;
        z1 += zt2[c*4+0]*v1.x + zt2[c*4+1]*v1.y + zt2[c*4+2]*v1.z + zt2[c*4+3]*v1.w;
        z2 += zt2[c*4+0]*v2.x + zt2[c*4+1]*v2.y + zt2[c*4+2]*v2.z + zt2[c*4+3]*v2.w;
    }

    // ---- bilinear corners ----
    const float r = 1.0f / (1.0f + __expf(-z0));
    const float p = (z1 + PI_F) / (2.0f * PI_F) * 4.0f;
    const float r0f = truncf(r), p0f = truncf(p);
    const float dr = r - r0f, dp = p - p0f;
    const int r0i = (int)r0f, p0i = (int)p0f;

    const float w0c = (1.0f - dr) * (1.0f - dp);
    const float w1c = (1.0f - dr) * dp;
    const float w2c = dr * (1.0f - dp);
    const float w3c = dr * dp;

    const int ri0 = min(r0i, 1);
    const int ri2 = min(r0i + 1, 1);
    const int pi0 = p0i & 3;
    const int pi1 = (p0i + 1) & 3;

    const int c0 = ri0 * 4 + pi0, c1 = ri0 * 4 + pi1;
    const int c2 = ri2 * 4 + pi0, c3 = ri2 * 4 + pi1;

    float cnt[8], wsum[8];
    #pragma unroll
    for (int n = 0; n < 8; ++n) {
        float cm = 0.0f, cw = 0.0f;
        if (c0 == n && w0c > 0.0f) { cm += 1.0f; cw += w0c; }
        if (c1 == n && w1c > 0.0f) { cm += 1.0f; cw += w1c; }
        if (c2 == n && w2c > 0.0f) { cm += 1.0f; cw += w2c; }
        if (c3 == n && w3c > 0.0f) { cm += 1.0f; cw += w3c; }
        cnt[n] = cm; wsum[n] = cw;
    }
    float mc[8], mw[8];
    #pragma unroll
    for (int n = 0; n < 8; ++n) {
        float ac = cnt[n], aw = wsum[n];
        #pragma unroll
        for (int j = 0; j < 4; ++j) {
            const float g = ang[n >> 1][j];
            ac += g * cnt[2 * j + (n & 1)];
            aw += g * wsum[2 * j + (n & 1)];
        }
        #pragma unroll
        for (int j = 0; j < 2; ++j) {
            const float g = rad[n >> 2][j];
            ac += g * cnt[4 * j + (n & 3)];
            aw += g * wsum[4 * j + (n & 3)];
        }
        mc[n] = ac; mw[n] = aw;
    }

    // ---- AoS store (R6 layout: 20 floats per element) ----
    float* wp = ws + (size_t)b * 20;
    float4 v0; v0.x = z0;    v0.y = z1;    v0.z = z2;    v0.w = 0.0f;
    float4 v1; v1.x = mc[0]; v1.y = mc[1]; v1.z = mc[2]; v1.w = mc[3];
    float4 v2; v2.x = mc[4]; v2.y = mc[5]; v2.z = mc[6]; v2.w = mc[7];
    float4 v3; v3.x = mw[0]; v3.y = mw[1]; v3.z = mw[2]; v3.w = mw[3];
    float4 v4; v4.x = mw[4]; v4.y = mw[5]; v4.z = mw[6]; v4.w = mw[7];
    reinterpret_cast<float4*>(wp)[0] = v0;
    reinterpret_cast<float4*>(wp)[1] = v1;
    reinterpret_cast<float4*>(wp)[2] = v2;
    reinterpret_cast<float4*>(wp)[3] = v3;
    reinterpret_cast<float4*>(wp)[4] = v4;
}

// ===================== kernel 2 (R6-verbatim) =====================
// LDS float layout:
// NW1[4][24]@0  NB1[24]@96  NW2[24][12]@120  NB2[12]@408
// RW1 8 cells x (12x24), cell stride padded 288->296 @420
// RB1[24]@2788  RW2[24][4]@2812  RB2[4]@2908  -> 2912 floats
#define K2_LDS 2912

extern "C" __global__ void __launch_bounds__(256, 6)
topo_k2(const float* __restrict__ ws,
        const float* __restrict__ nw1, const float* __restrict__ nb1,
        const float* __restrict__ nw2, const float* __restrict__ nb2,
        const float* __restrict__ rw1, const float* __restrict__ rb1,
        const float* __restrict__ rw2, const float* __restrict__ rb2,
        float* __restrict__ out, int B)
{
    __shared__ float wf[K2_LDS];
    const float4* wq = reinterpret_cast<const float4*>(wf);

    {
        const int tt = threadIdx.x;
        for (int i = tt; i < 96;   i += 256) wf[i]        = nw1[i];
        for (int i = tt; i < 24;   i += 256) wf[96 + i]   = nb1[i];
        for (int i = tt; i < 288;  i += 256) wf[120 + i]  = nw2[i];
        for (int i = tt; i < 12;   i += 256) wf[408 + i]  = nb2[i];
        for (int i = tt; i < 2304; i += 256) {
            const int cell = i / 288, rem = i - cell * 288;
            wf[420 + cell * 296 + rem] = rw1[i];
        }
        for (int i = tt; i < 24;   i += 256) wf[2788 + i] = rb1[i];
        for (int i = tt; i < 96;   i += 256) wf[2812 + i] = rw2[i];
        for (int i = tt; i < 4;    i += 256) wf[2908 + i] = rb2[i];
    }
    __syncthreads();

    const int tid  = blockIdx.x * blockDim.x + threadIdx.x;
    const int lane = tid & 3;           // owns cells 2*lane, 2*lane+1
    const int b    = tid >> 2;
    if (b >= B) return;

    // per-element state from ws
    const float* wp = ws + (size_t)b * 20;
    const float4 zv = *reinterpret_cast<const float4*>(wp);
    const float2 mc2 = *reinterpret_cast<const float2*>(wp + 4 + 2 * lane);
    const float2 mw2 = *reinterpret_cast<const float2*>(wp + 12 + 2 * lane);
    const float z0 = zv.x, z1 = zv.y, z2 = zv.z;

    float t[24];
    #pragma unroll
    for (int j = 0; j < 24; ++j) t[j] = 0.0f;

    #pragma unroll
    for (int cc = 0; cc < 2; ++cc) {
        const float mc_ = cc ? mc2.y : mc2.x;
        const float mw_ = cc ? mw2.y : mw2.x;
        const float f0 = mc_ * z0, f1 = mc_ * z1, f2 = mc_ * z2;

        float ho[12];
        {
            float4 bA = wq[102], bB = wq[103], bC = wq[104];
            ho[0] = bA.x; ho[1]  = bA.y; ho[2]  = bA.z; ho[3]  = bA.w;
            ho[4] = bB.x; ho[5]  = bB.y; ho[6]  = bB.z; ho[7]  = bB.w;
            ho[8] = bC.x; ho[9]  = bC.y; ho[10] = bC.z; ho[11] = bC.w;
        }
        #pragma unroll
        for (int c = 0; c < 6; ++c) {
            float4 b1 = wq[24 + c];
            float4 u0 = wq[c],      u1 = wq[6 + c];
            float4 u2 = wq[12 + c], u3 = wq[18 + c];
            float h[4];
            h[0] = fast_tanh(b1.x + f0*u0.x + f1*u1.x + f2*u2.x + mw_*u3.x);
            h[1] = fast_tanh(b1.y + f0*u0.y + f1*u1.y + f2*u2.y + mw_*u3.y);
            h[2] = fast_tanh(b1.z + f0*u0.z + f1*u1.z + f2*u2.z + mw_*u3.z);
            h[3] = fast_tanh(b1.w + f0*u0.w + f1*u1.w + f2*u2.w + mw_*u3.w);
            #pragma unroll
            for (int jj = 0; jj < 4; ++jj) {
                const int j = c * 4 + jj;
                const float hj = h[jj];
                float4 n0 = wq[30 + j * 3], n1 = wq[31 + j * 3], n2 = wq[32 + j * 3];
                ho[0] += hj*n0.x; ho[1]  += hj*n0.y; ho[2]  += hj*n0.z; ho[3]  += hj*n0.w;
                ho[4] += hj*n1.x; ho[5]  += hj*n1.y; ho[6]  += hj*n1.z; ho[7]  += hj*n1.w;
                ho[8] += hj*n2.x; ho[9]  += hj*n2.y; ho[10] += hj*n2.z; ho[11] += hj*n2.w;
            }
        }
        // t += ho . rw1[cell]; cell = 2*lane+cc, padded stride 296 floats
        const int cellbase = 420 + (2 * lane + cc) * 296;   // dword offset
        #pragma unroll
        for (int d = 0; d < 12; ++d) {
            const float hd = ho[d];
            const int qb = (cellbase >> 2) + d * 6;          // float4 index
            #pragma unroll
            for (int c = 0; c < 6; ++c) {
                float4 rv = wq[qb + c];
                t[c*4+0] += hd * rv.x; t[c*4+1] += hd * rv.y;
                t[c*4+2] += hd * rv.z; t[c*4+3] += hd * rv.w;
            }
        }
        __builtin_amdgcn_sched_barrier(0);
    }

    // reduce across the 4 lanes (8 cells), add rb1
    #pragma unroll
    for (int j = 0; j < 24; ++j) t[j] = quad_sum(t[j]) + wf[2788 + j];

    // readout layer 2 (redundant in quad; lane 0 stores)
    float4 ob = wq[727];
    float o0 = ob.x, o1 = ob.y, o2 = ob.z, o3 = ob.w;
    #pragma unroll
    for (int j = 0; j < 24; ++j) {
        const float tv = fast_tanh(t[j]);
        float4 rv = wq[703 + j];
        o0 += tv * rv.x; o1 += tv * rv.y; o2 += tv * rv.z; o3 += tv * rv.w;
    }
    if (lane == 0) {
        float4 ov; ov.x = o0; ov.y = o1; ov.z = o2; ov.w = o3;
        *reinterpret_cast<float4*>(out + (size_t)b * 4) = ov;
    }
}

// ===================== fallback fused kernel =====================
extern "C" __global__ void __launch_bounds__(256, 2)
topo_fused(const float* __restrict__ x,
           const float* __restrict__ ew1, const float* __restrict__ eb1,
           const float* __restrict__ ew2, const float* __restrict__ eb2,
           const float* __restrict__ ew3, const float* __restrict__ eb3,
           const float* __restrict__ nw1, const float* __restrict__ nb1,
           const float* __restrict__ nw2, const float* __restrict__ nb2,
           const float* __restrict__ alog, const float* __restrict__ rlog,
           const float* __restrict__ rw1, const float* __restrict__ rb1,
           const float* __restrict__ rw2, const float* __restrict__ rb2,
           float* __restrict__ out, int B)
{
    const int b = blockIdx.x * blockDim.x + threadIdx.x;
    if (b >= B) return;

    float ang[4][4];
    {
        float m = fmaxf(fmaxf(alog[0], alog[1]), fmaxf(alog[2], alog[3]));
        float e0 = __expf(alog[0] - m), e1 = __expf(alog[1] - m);
        float e2 = __expf(alog[2] - m), e3 = __expf(alog[3] - m);
        float s = e0 + e1 + e2 + e3;
        float sm[4] = { e0 / s, e1 / s, e2 / s, e3 / s };
        #pragma unroll
        for (int i = 0; i < 4; ++i) {
            const int jn = (i + 3) & 3, jp = (i + 1) & 3;
            float inv = 1.0f / fmaxf(sm[jn] + sm[jp], 1e-6f);
            #pragma unroll
            for (int j = 0; j < 4; ++j) {
                float adj = (j == jn || j == jp) ? 1.0f : 0.0f;
                ang[i][j] = sm[j] * adj * inv;
            }
        }
    }
    float rad[2][2];
    {
        float m = fmaxf(rlog[0], rlog[1]);
        float f0 = __expf(rlog[0] - m), f1 = __expf(rlog[1] - m);
        float fs = f0 + f1;
        float sm0 = f0 / fs, sm1 = f1 / fs;
        rad[0][0] = 0.0f; rad[0][1] = sm1 / fmaxf(sm1, 1e-6f);
        rad[1][1] = 0.0f; rad[1][0] = sm0 / fmaxf(sm0, 1e-6f);
    }

    const float4 xv = *reinterpret_cast<const float4*>(x + (size_t)b * 60 + 56);
    float zt[24];
    #pragma unroll
    for (int j = 0; j < 24; ++j) {
        float a = eb1[j];
        a += xv.x * ew1[j];
        a += xv.y * ew1[24 + j];
        a += xv.z * ew1[48 + j];
        a += xv.w * ew1[72 + j];
        zt[j] = fast_tanh(a);
    }
    float z0 = eb3[0], z1 = eb3[1], z2 = eb3[2];
    #pragma unroll
    for (int j = 0; j < 24; ++j) {
        float a = eb2[j];
        #pragma unroll
        for (int k = 0; k < 24; ++k) a += zt[k] * ew2[k * 24 + j];
        const float z2t = fast_tanh(a);
        z0 += z2t * ew3[j * 3 + 0];
        z1 += z2t * ew3[j * 3 + 1];
        z2 += z2t * ew3[j * 3 + 2];
    }

    const float r = 1.0f / (1.0f + __expf(-z0));
    const float p = (z1 + PI_F) / (2.0f * PI_F) * 4.0f;
    const float r0f = truncf(r), p0f = truncf(p);
    const float dr = r - r0f, dp = p - p0f;
    const int r0i = (int)r0f, p0i = (int)p0f;
    const float w0c = (1.0f - dr) * (1.0f - dp);
    const float w1c = (1.0f - dr) * dp;
    const float w2c = dr * (1.0f - dp);
    const float w3c = dr * dp;
    const int ri0 = min(r0i, 1);
    const int ri2 = min(r0i + 1, 1);
    const int pi0 = p0i & 3;
    const int pi1 = (p0i + 1) & 3;
    const int c0 = ri0 * 4 + pi0, c1 = ri0 * 4 + pi1;
    const int c2 = ri2 * 4 + pi0, c3 = ri2 * 4 + pi1;

    float cnt[8], wsum[8];
    #pragma unroll
    for (int n = 0; n < 8; ++n) {
        float cm = 0.0f, cw = 0.0f;
        if (c0 == n && w0c > 0.0f) { cm += 1.0f; cw += w0c; }
        if (c1 == n && w1c > 0.0f) { cm += 1.0f; cw += w1c; }
        if (c2 == n && w2c > 0.0f) { cm += 1.0f; cw += w2c; }
        if (c3 == n && w3c > 0.0f) { cm += 1.0f; cw += w3c; }
        cnt[n] = cm; wsum[n] = cw;
    }
    float mc[8], mw[8];
    #pragma unroll
    for (int n = 0; n < 8; ++n) {
        float ac = cnt[n], aw = wsum[n];
        #pragma unroll
        for (int j = 0; j < 4; ++j) {
            const float g = ang[n >> 1][j];
            ac += g * cnt[2 * j + (n & 1)];
            aw += g * wsum[2 * j + (n & 1)];
        }
        #pragma unroll
        for (int j = 0; j < 2; ++j) {
            const float g = rad[n >> 2][j];
            ac += g * cnt[4 * j + (n & 3)];
            aw += g * wsum[4 * j + (n & 3)];
        }
        mc[n] = ac; mw[n] = aw;
    }

    float t[24];
    #pragma unroll
    for (int j = 0; j < 24; ++j) t[j] = rb1[j];
    #pragma unroll
    for (int n = 0; n < 8; ++n) {
        const float f0 = mc[n] * z0, f1 = mc[n] * z1, f2 = mc[n] * z2;
        float ho[12];
        #pragma unroll
        for (int d = 0; d < 12; ++d) ho[d] = nb2[d];
        #pragma unroll
        for (int j = 0; j < 24; ++j) {
            const float hj = fast_tanh(nb1[j] + f0 * nw1[j] + f1 * nw1[24 + j]
                                       + f2 * nw1[48 + j] + mw[n] * nw1[72 + j]);
            #pragma unroll
            for (int d = 0; d < 12; ++d) ho[d] += hj * nw2[j * 12 + d];
        }
        #pragma unroll
        for (int d = 0; d < 12; ++d) {
            const int rbase = (n * 12 + d) * 24;
            #pragma unroll
            for (int j2 = 0; j2 < 24; ++j2) t[j2] += ho[d] * rw1[rbase + j2];
        }
    }

    float o0 = rb2[0], o1 = rb2[1], o2 = rb2[2], o3 = rb2[3];
    #pragma unroll
    for (int j = 0; j < 24; ++j) {
        const float tt = fast_tanh(t[j]);
        o0 += tt * rw2[j * 4 + 0];
        o1 += tt * rw2[j * 4 + 1];
        o2 += tt * rw2[j * 4 + 2];
        o3 += tt * rw2[j * 4 + 3];
    }
    float4 ov; ov.x = o0; ov.y = o1; ov.z = o2; ov.w = o3;
    *reinterpret_cast<float4*>(out + (size_t)b * 4) = ov;
}

extern "C" void kernel_launch(void* const* d_in, const int* in_sizes, int n_in,
                              void* d_out, int out_size, void* d_ws, size_t ws_size,
                              hipStream_t stream) {
    const float* x    = (const float*)d_in[0];
    const float* ew1  = (const float*)d_in[1];
    const float* eb1  = (const float*)d_in[2];
    const float* ew2  = (const float*)d_in[3];
    const float* eb2  = (const float*)d_in[4];
    const float* ew3  = (const float*)d_in[5];
    const float* eb3  = (const float*)d_in[6];
    const float* nw1  = (const float*)d_in[7];
    const float* nb1  = (const float*)d_in[8];
    const float* nw2  = (const float*)d_in[9];
    const float* nb2  = (const float*)d_in[10];
    const float* alog = (const float*)d_in[11];
    const float* rlog = (const float*)d_in[12];
    const float* rw1  = (const float*)d_in[13];
    const float* rb1  = (const float*)d_in[14];
    const float* rw2  = (const float*)d_in[15];
    const float* rb2  = (const float*)d_in[16];
    float* out = (float*)d_out;

    const int B = in_sizes[0] / 60;   // x is (B, 15, 4)
    const size_t ws_needed = (size_t)B * 20 * sizeof(float);

    if (ws_size >= ws_needed) {
        float* ws = (float*)d_ws;
        const int g1 = (B + 255) / 256;
        topo_k1<<<g1, 256, 0, stream>>>(x, ew1, eb1, ew2, eb2, ew3, eb3,
                                        alog, rlog, ws, B);
        const long long tot2 = (long long)B * 4;
        const int g2 = (int)((tot2 + 255) / 256);
        topo_k2<<<g2, 256, 0, stream>>>(ws, nw1, nb1, nw2, nb2,
                                        rw1, rb1, rw2, rb2, out, B);
    } else {
        const int g = (B + 255) / 256;
        topo_fused<<<g, 256, 0, stream>>>(
            x, ew1, eb1, ew2, eb2, ew3, eb3, nw1, nb1, nw2, nb2,
            alog, rlog, rw1, rb1, rw2, rb2, out, B);
    }
}